// Round 7
// baseline (2222.452 us; speedup 1.0000x reference)
//
#include <hip/hip_runtime.h>
#include <hip/hip_bf16.h>
#include <stdint.h>

typedef float f32x4 __attribute__((ext_vector_type(4)));
typedef short bf16x8 __attribute__((ext_vector_type(8)));

__device__ __forceinline__ ushort to_bf16(float f) {
    union { float f; uint32_t u; } v; v.f = f;
    uint32_t u = v.u;
    return (ushort)((u + 0x7fffu + ((u >> 16) & 1u)) >> 16);   // RNE
}
__device__ __forceinline__ float sigmoid_(float x) { return 1.0f / (1.0f + __expf(-x)); }
__device__ __forceinline__ float tanh_(float x)    { return 1.0f - 2.0f / (__expf(2.0f * x) + 1.0f); }

// Swizzled concat weight W'[g][k] = (k<384 ? w_ih : w_hh), bf16; fragment layout:
// elem ((tile*24 + kc)*64 + quad*16 + (g&15))*8 + j  for k = kc*32 + quad*8 + j
__global__ void prep_w(const float* __restrict__ w_ih, const float* __restrict__ w_hh,
                       ushort* __restrict__ wswz) {
    int tid = blockIdx.x * blockDim.x + threadIdx.x;   // 1152 * 96
    if (tid >= 1152 * 96) return;
    int g  = tid / 96;
    int k  = (tid % 96) * 8;
    int kc = k >> 5;
    int q  = (k >> 3) & 3;
    int tile = g >> 4;
    int lane = q * 16 + (g & 15);
    ushort* dst = wswz + ((size_t)(tile * 24 + kc) * 64 + lane) * 8;
    const float* src = (k < 384) ? (w_ih + (size_t)g * 384 + k)
                                 : (w_hh + (size_t)g * 384 + (k - 384));
#pragma unroll
    for (int j = 0; j < 8; ++j) dst[j] = to_bf16(src[j]);
}

__global__ void embed_gather(const int* __restrict__ tok, const float* __restrict__ table,
                             ushort* __restrict__ xleaf, int n_leaves) {
    int tid = blockIdx.x * blockDim.x + threadIdx.x;   // n_leaves * 48
    if (tid >= n_leaves * 48) return;
    int leaf = tid / 48, i = tid % 48;
    const float* src = table + (size_t)tok[leaf] * 384 + i * 8;
    bf16x8 v;
#pragma unroll
    for (int j = 0; j < 8; ++j) v[j] = (short)to_bf16(src[j]);
    *(bf16x8*)(xleaf + (size_t)leaf * 384 + i * 8) = v;
}

struct TreeParams {
    const ushort* XA;          // leaf x, bf16 [32768*384]
    const ushort* W;           // swizzled weights
    const float* bih;
    const float* bhh;
    float* fout;               // d_out [384]
    ushort* HB[5];             // bf16 h slots 0..7   [8*P*384]
    float*  HT[5];             // f32  h slots 0..7   [8*P*384]
    ushort* Xo[5];             // level outputs, bf16 [P*384]
    unsigned int* ctr;         // barrier counters (zeroed per call)
    int* xcc;                  // per-block XCD id [384]
};

// Fenced device barrier (correct across XCDs): release/acquire with L2 wb+inv.
__device__ __forceinline__ void barrier_fence(unsigned int* c, unsigned int target) {
    __syncthreads();
    if (threadIdx.x == 0) {
        __threadfence();
        __hip_atomic_fetch_add(c, 1u, __ATOMIC_RELEASE, __HIP_MEMORY_SCOPE_AGENT);
        while (__hip_atomic_load(c, __ATOMIC_ACQUIRE, __HIP_MEMORY_SCOPE_AGENT) < target)
            __builtin_amdgcn_s_sleep(8);
        __threadfence();
    }
    __syncthreads();
}

// Fast group barrier: NO cache maintenance. Valid only when all participants
// share one XCD (verified at runtime): vector L1 is write-through to L2,
// __syncthreads drains vmcnt before s_barrier, and every cross-block address
// consumed after this barrier is cold in the consumer's L1 (unique per (lv,t)).
__device__ __forceinline__ void barrier_fast(unsigned int* c, unsigned int target) {
    __syncthreads();
    if (threadIdx.x == 0) {
        __hip_atomic_fetch_add(c, 1u, __ATOMIC_RELAXED, __HIP_MEMORY_SCOPE_AGENT);
        while (__hip_atomic_load(c, __ATOMIC_RELAXED, __HIP_MEMORY_SCOPE_AGENT) < target)
            __builtin_amdgcn_s_sleep(1);
    }
    __syncthreads();
}

#define MFMA(a, b, c) __builtin_amdgcn_mfma_f32_16x16x32_bf16((a), (b), (c), 0, 0, 0)

// Persistent whole-tree kernel. Grid (16 groups, 24 ds) = 384 blocks, 2/CU
// (73.7 KB LDS), all co-resident. Block (bx,ds): dims [ds*16, ds*16+16) --
// gate triple r,z,n staged in LDS once -> GRU update lane-local. Wave w owns
// m-tiles bx*16 + i*4 + w (i=0..3). Intra-level step sync: 24-block group
// barrier (fast path when group is XCD-uniform; fenced fallback otherwise).
// Level transitions: fenced 384-block barrier (cross-XCD x/h0 handoff).
__global__ __launch_bounds__(256, 2)
void tree_kernel(TreeParams p) {
    __shared__ ushort LW[3 * 12288];   // slots r,z,n: [slot][kc][lane*8]
    const int tid = threadIdx.x;
    const int wave = tid >> 6, lane = tid & 63;
    const int quad = lane >> 4, col = lane & 15;
    const int bx = blockIdx.x, ds = blockIdx.y;
    const int blkId = bx + 16 * ds;

    // Stage this block's 3 weight tiles (r,z,n for its 16 dims) into LDS once.
#pragma unroll
    for (int s = 0; s < 3; ++s) {
        const uint4* src = (const uint4*)(p.W + (size_t)(s * 24 + ds) * 12288);
        uint4* dst = (uint4*)(LW + s * 12288);
        for (int c = tid; c < 1536; c += 256) dst[c] = src[c];
    }

    const int d = ds * 16 + col;
    const float br = p.bih[d] + p.bhh[d];
    const float bz = p.bih[384 + d] + p.bhh[384 + d];
    const float bi = p.bih[768 + d];
    const float bh = p.bhh[768 + d];
    __syncthreads();

    // Runtime XCD-uniformity check for this block's group (the 24 ds-blocks).
    int myxcc;
    asm volatile("s_getreg_b32 %0, hwreg(HW_REG_XCC_ID)" : "=s"(myxcc));
    if (tid == 0) p.xcc[blkId] = myxcc;
    barrier_fence(&p.ctr[645], 384u);
    bool fastOK = true;
    for (int k = 0; k < 24; ++k) fastOK = fastOK && (p.xcc[bx + 16 * k] == myxcc);

    const int Ps[5] = {4096, 512, 64, 8, 1};
    const bf16x8 zf = {0, 0, 0, 0, 0, 0, 0, 0};
    const f32x4 z4 = {0.f, 0.f, 0.f, 0.f};

    for (int lv = 0; lv < 5; ++lv) {
        const int P = Ps[lv];
        const int nTiles = (P + 15) >> 4;
        const int nGroups = (nTiles + 15) >> 4;
        const size_t N = (size_t)P * 384;
        const ushort* Xc = (lv == 0) ? p.XA : p.Xo[lv - 1];
        ushort* HB = p.HB[lv];
        float*  HT = p.HT[lv];
        ushort* Xo = p.Xo[lv];

        if (bx < nGroups) {
            int ti[4], par[4]; bool tv[4], av[4];
#pragma unroll
            for (int i = 0; i < 4; ++i) {
                ti[i] = bx * 16 + i * 4 + wave;
                tv[i] = ti[i] < nTiles;
                par[i] = ti[i] * 16 + col;
                av[i] = tv[i] && (par[i] < P);
            }

            for (int t = 0; t < 8; ++t) {
                if (t) {
                    unsigned int* c = &p.ctr[(lv * 8 + t) * 16 + bx];
                    if (fastOK) barrier_fast(c, 24u); else barrier_fence(c, 24u);
                }
                const int child = 7 - t;
                const bool hz = (lv == 0 && t == 0);
                const ushort* HBp = HB + (size_t)t * N;
                const float*  HTp = HT + (size_t)t * N;

                float hp[4][4];
#pragma unroll
                for (int i = 0; i < 4; ++i)
#pragma unroll
                    for (int r = 0; r < 4; ++r) {
                        const int m = ti[i] * 16 + quad * 4 + r;
                        hp[i][r] = (!hz && tv[i] && m < P) ? HTp[(size_t)m * 384 + d] : 0.0f;
                    }

                f32x4 ar[4], az[4], an1[4], an2[4];
#pragma unroll
                for (int i = 0; i < 4; ++i) { ar[i] = z4; az[i] = z4; an1[i] = z4; an2[i] = z4; }

                // x half (W_ih columns, kc 0..11)
#pragma unroll
                for (int kc = 0; kc < 12; ++kc) {
                    bf16x8 a[4];
#pragma unroll
                    for (int i = 0; i < 4; ++i)
                        a[i] = av[i] ? *(const bf16x8*)(Xc + ((size_t)par[i] * 8 + child) * 384
                                                        + kc * 32 + quad * 8)
                                     : zf;
                    const bf16x8 bR = *(const bf16x8*)(LW + (0 * 24 + kc) * 512 + lane * 8);
                    const bf16x8 bZ = *(const bf16x8*)(LW + (1 * 24 + kc) * 512 + lane * 8);
                    const bf16x8 bN = *(const bf16x8*)(LW + (2 * 24 + kc) * 512 + lane * 8);
#pragma unroll
                    for (int i = 0; i < 4; ++i) {
                        ar[i]  = MFMA(a[i], bR, ar[i]);
                        az[i]  = MFMA(a[i], bZ, az[i]);
                        an1[i] = MFMA(a[i], bN, an1[i]);
                    }
                }
                // h half (W_hh columns, kc 12..23) — skipped when h == 0
                if (!hz) {
#pragma unroll
                    for (int kc = 0; kc < 12; ++kc) {
                        bf16x8 a[4];
#pragma unroll
                        for (int i = 0; i < 4; ++i)
                            a[i] = av[i] ? *(const bf16x8*)(HBp + (size_t)par[i] * 384
                                                            + kc * 32 + quad * 8)
                                         : zf;
                        const bf16x8 bR = *(const bf16x8*)(LW + (0 * 24 + 12 + kc) * 512 + lane * 8);
                        const bf16x8 bZ = *(const bf16x8*)(LW + (1 * 24 + 12 + kc) * 512 + lane * 8);
                        const bf16x8 bN = *(const bf16x8*)(LW + (2 * 24 + 12 + kc) * 512 + lane * 8);
#pragma unroll
                        for (int i = 0; i < 4; ++i) {
                            ar[i]  = MFMA(a[i], bR, ar[i]);
                            az[i]  = MFMA(a[i], bZ, az[i]);
                            an2[i] = MFMA(a[i], bN, an2[i]);
                        }
                    }
                }

                // epilogue: GRU update (lane-local), per-quad child-mean at t==7
                float s4[4];
#pragma unroll
                for (int i = 0; i < 4; ++i) {
                    s4[i] = 0.0f;
#pragma unroll
                    for (int r = 0; r < 4; ++r) {
                        const int m = ti[i] * 16 + quad * 4 + r;
                        if (tv[i] && m < P) {
                            const size_t idx = (size_t)m * 384 + d;
                            const float rv = sigmoid_(ar[i][r] + br);
                            const float zv = sigmoid_(az[i][r] + bz);
                            const float nv = tanh_(an1[i][r] + bi + rv * (an2[i][r] + bh));
                            const float hn = (1.0f - zv) * nv + zv * hp[i][r];
                            s4[i] += hn;
                            if (t < 7) {
                                HT[(size_t)(t + 1) * N + idx] = hn;
                                HB[(size_t)(t + 1) * N + idx] = to_bf16(hn);
                            } else {
                                // node out = mean(h1..h8) = (h1..h6 + hp(=h7) + hn)/8
                                float xs = hn + hp[i][r];
#pragma unroll
                                for (int s = 1; s <= 6; ++s) xs += HT[(size_t)s * N + idx];
                                const float xo = xs * 0.125f;
                                Xo[idx] = to_bf16(xo);
                                if (lv == 4 && m == 0) p.fout[d] = xo;
                            }
                        }
                    }
                }

                // t==7: emit parent h0 = mean of 8 children h8 (quad-pair shfl)
                if (t == 7 && lv < 4) {
                    const int Pn = Ps[lv + 1];
                    float*  HTn = p.HT[lv + 1];
                    ushort* HBn = p.HB[lv + 1];
#pragma unroll
                    for (int i = 0; i < 4; ++i) {
                        if (!tv[i]) continue;
                        const float o = __shfl_xor(s4[i], 16, 64);   // quads (0,1),(2,3)
                        if ((quad & 1) == 0) {
                            const int pnode = 2 * ti[i] + (quad >> 1);
                            if (pnode < Pn) {
                                const float h0 = (s4[i] + o) * 0.125f;
                                HTn[(size_t)pnode * 384 + d] = h0;
                                HBn[(size_t)pnode * 384 + d] = to_bf16(h0);
                            }
                        }
                    }
                }
            }
        }

        if (lv < 4) barrier_fence(&p.ctr[640 + lv], 384u);
    }
}

extern "C" void kernel_launch(void* const* d_in, const int* in_sizes, int n_in,
                              void* d_out, int out_size, void* d_ws, size_t ws_size,
                              hipStream_t stream) {
    const int*   tok   = (const int*)d_in[0];
    const float* table = (const float*)d_in[1];
    const float* w_ih  = (const float*)d_in[2];
    const float* w_hh  = (const float*)d_in[3];
    const float* b_ih  = (const float*)d_in[4];
    const float* b_hh  = (const float*)d_in[5];
    float* out = (float*)d_out;

    char* ws = (char*)d_ws;
    size_t off = 0;
    auto alloc = [&](size_t bytes) -> void* {
        void* p = ws + off;
        off = (off + bytes + 255) & ~(size_t)255;
        return p;
    };
    ushort* wswz = (ushort*)alloc((size_t)1152 * 768 * 2);
    ushort* XA   = (ushort*)alloc((size_t)32768 * 384 * 2);

    TreeParams tp;
    tp.XA = XA; tp.W = wswz; tp.bih = b_ih; tp.bhh = b_hh; tp.fout = out;
    const int Ps[5] = {4096, 512, 64, 8, 1};
    for (int lv = 0; lv < 5; ++lv) {
        size_t N = (size_t)Ps[lv] * 384;
        tp.HT[lv] = (float*) alloc(8 * N * 4);
        tp.HB[lv] = (ushort*)alloc(8 * N * 2);
        tp.Xo[lv] = (ushort*)alloc(N * 2);
    }
    tp.ctr = (unsigned int*)alloc(1024 * 4);
    tp.xcc = (int*)alloc(384 * 4);

    hipMemsetAsync(tp.ctr, 0, 1024 * 4, stream);
    prep_w<<<(1152 * 96 + 255) / 256, 256, 0, stream>>>(w_ih, w_hh, wswz);
    embed_gather<<<(32768 * 48 + 255) / 256, 256, 0, stream>>>(tok, table, XA, 32768);

    tree_kernel<<<dim3(16, 24), 256, 0, stream>>>(tp);
}

// Round 8
// 932.132 us; speedup vs baseline: 2.3843x; 2.3843x over previous
//
#include <hip/hip_runtime.h>
#include <hip/hip_bf16.h>
#include <stdint.h>

typedef float f32x4 __attribute__((ext_vector_type(4)));
typedef short bf16x8 __attribute__((ext_vector_type(8)));

__device__ __forceinline__ ushort to_bf16(float f) {
    union { float f; uint32_t u; } v; v.f = f;
    uint32_t u = v.u;
    return (ushort)((u + 0x7fffu + ((u >> 16) & 1u)) >> 16);   // RNE
}
__device__ __forceinline__ float sigmoid_(float x) { return 1.0f / (1.0f + __expf(-x)); }
__device__ __forceinline__ float tanh_(float x)    { return 1.0f - 2.0f / (__expf(2.0f * x) + 1.0f); }

// Swizzled concat weight W'[g][k] = (k<384 ? w_ih : w_hh), bf16; fragment layout:
// elem ((tile*24 + kc)*64 + quad*16 + (g&15))*8 + j  for k = kc*32 + quad*8 + j
__global__ void prep_w(const float* __restrict__ w_ih, const float* __restrict__ w_hh,
                       ushort* __restrict__ wswz) {
    int tid = blockIdx.x * blockDim.x + threadIdx.x;   // 1152 * 96
    if (tid >= 1152 * 96) return;
    int g  = tid / 96;
    int k  = (tid % 96) * 8;
    int kc = k >> 5;
    int q  = (k >> 3) & 3;
    int tile = g >> 4;
    int lane = q * 16 + (g & 15);
    ushort* dst = wswz + ((size_t)(tile * 24 + kc) * 64 + lane) * 8;
    const float* src = (k < 384) ? (w_ih + (size_t)g * 384 + k)
                                 : (w_hh + (size_t)g * 384 + (k - 384));
#pragma unroll
    for (int j = 0; j < 8; ++j) dst[j] = to_bf16(src[j]);
}

__global__ void embed_gather(const int* __restrict__ tok, const float* __restrict__ table,
                             ushort* __restrict__ xleaf, int n_leaves) {
    int tid = blockIdx.x * blockDim.x + threadIdx.x;   // n_leaves * 48
    if (tid >= n_leaves * 48) return;
    int leaf = tid / 48, i = tid % 48;
    const float* src = table + (size_t)tok[leaf] * 384 + i * 8;
    bf16x8 v;
#pragma unroll
    for (int j = 0; j < 8; ++j) v[j] = (short)to_bf16(src[j]);
    *(bf16x8*)(xleaf + (size_t)leaf * 384 + i * 8) = v;
}

#define MFMA(a, b, c) __builtin_amdgcn_mfma_f32_16x16x32_bf16((a), (b), (c), 0, 0, 0)

// One GRU step, one launch (the launch boundary IS the barrier — in-kernel
// cross-block barriers fence-storm on this chip; measured r6/r7).
// No LDS, no __syncthreads. Block = 256 thr (4 waves); wave owns 32 rows
// (2 m-tiles); block owns 32 dims (ds = blockIdx.y in [0,12), j = 2 16-col
// tiles per gate). Gate triple (r,z,n) for (m,d) lands in ONE lane -> GRU
// update lane-local. Grid (gx, 12), gx % 8 == 0 so the 12 ds-blocks of an
// m-group colocate on one XCD (x/h L2 locality).
// State: HT = 8 f32 slots (slot t = h entering step t), HB bf16 mirror.
// Step t reads slot t, writes slot t+1 (t<7). At t==7: Xo = mean(h1..h8),
// parent h0 = mean of children h8 via quad-pair shfl -> next level slot 0.
// flags: 1 = h_prev zero (leaf t0), 2 = last step.
__global__ __launch_bounds__(256, 3)
void gru_step(const ushort* __restrict__ Xc, ushort* __restrict__ HB,
              float* __restrict__ HT, const ushort* __restrict__ W,
              const float* __restrict__ b_ih, const float* __restrict__ b_hh,
              ushort* __restrict__ Xo, float* __restrict__ HTn,
              ushort* __restrict__ HBn, float* __restrict__ fout,
              int P, int Pn, int t, int flags) {
    const int wave = threadIdx.x >> 6, lane = threadIdx.x & 63;
    const int quad = lane >> 4, col = lane & 15;
    const int m0 = (blockIdx.x * 4 + wave) * 32;
    if (m0 >= P) return;
    const int ds = blockIdx.y;
    const bool hz = (flags & 1) != 0, last = (flags & 2) != 0;
    const bool do2 = (m0 + 16) < P;                  // wave-uniform
    const int child = 7 - t;
    const size_t N = (size_t)P * 384;

    const ushort* HBp = HB + (size_t)t * N;
    const float*  HTp = HT + (size_t)t * N;

    const int par0 = m0 + col, par1 = m0 + 16 + col;
    const bool av0 = par0 < P, av1 = par1 < P;
    const ushort* xr0 = Xc + ((size_t)par0 * 8 + child) * 384 + quad * 8;
    const ushort* xr1 = Xc + ((size_t)par1 * 8 + child) * 384 + quad * 8;
    const ushort* hr0 = HBp + (size_t)par0 * 384 + quad * 8;
    const ushort* hr1 = HBp + (size_t)par1 * 384 + quad * 8;
    const ushort* Wl = W + (size_t)lane * 8;
    // B tiles for dims ds*32 + j*16: r: 2ds+j, z: 24+2ds+j, n: 48+2ds+j
    size_t oR[2], oZ[2], oN[2];
#pragma unroll
    for (int j = 0; j < 2; ++j) {
        oR[j] = (size_t)(2 * ds + j) * 12288;
        oZ[j] = (size_t)(24 + 2 * ds + j) * 12288;
        oN[j] = (size_t)(48 + 2 * ds + j) * 12288;
    }

    int dj[2]; float br[2], bz[2], bi[2], bh[2];
#pragma unroll
    for (int j = 0; j < 2; ++j) {
        dj[j] = ds * 32 + j * 16 + col;
        br[j] = b_ih[dj[j]] + b_hh[dj[j]];
        bz[j] = b_ih[384 + dj[j]] + b_hh[384 + dj[j]];
        bi[j] = b_ih[768 + dj[j]];
        bh[j] = b_hh[768 + dj[j]];
    }
    float hp[2][2][4];                               // [j][mt][r]
#pragma unroll
    for (int j = 0; j < 2; ++j)
#pragma unroll
        for (int mt = 0; mt < 2; ++mt)
#pragma unroll
            for (int r = 0; r < 4; ++r) {
                const int m = m0 + mt * 16 + quad * 4 + r;
                hp[j][mt][r] = (!hz && m < P) ? HTp[(size_t)m * 384 + dj[j]] : 0.0f;
            }

    const f32x4 z4 = (f32x4){0.f, 0.f, 0.f, 0.f};
    const bf16x8 zf = (bf16x8){0, 0, 0, 0, 0, 0, 0, 0};
    f32x4 ar[2][2], az[2][2], an1[2][2], an2[2][2];  // [j][mt]
#pragma unroll
    for (int j = 0; j < 2; ++j)
#pragma unroll
        for (int mt = 0; mt < 2; ++mt) {
            ar[j][mt] = z4; az[j][mt] = z4; an1[j][mt] = z4; an2[j][mt] = z4;
        }

    // x half (W_ih columns, kc 0..11)
#pragma unroll
    for (int kc = 0; kc < 12; ++kc) {
        bf16x8 a0 = av0 ? *(const bf16x8*)(xr0 + kc * 32) : zf;
        bf16x8 a1 = (do2 && av1) ? *(const bf16x8*)(xr1 + kc * 32) : zf;
        const size_t kb = (size_t)kc * 512;
#pragma unroll
        for (int j = 0; j < 2; ++j) {
            const bf16x8 bR = *(const bf16x8*)(Wl + oR[j] + kb);
            const bf16x8 bZ = *(const bf16x8*)(Wl + oZ[j] + kb);
            const bf16x8 bN = *(const bf16x8*)(Wl + oN[j] + kb);
            ar[j][0]  = MFMA(a0, bR, ar[j][0]);
            az[j][0]  = MFMA(a0, bZ, az[j][0]);
            an1[j][0] = MFMA(a0, bN, an1[j][0]);
            if (do2) {
                ar[j][1]  = MFMA(a1, bR, ar[j][1]);
                az[j][1]  = MFMA(a1, bZ, az[j][1]);
                an1[j][1] = MFMA(a1, bN, an1[j][1]);
            }
        }
    }
    // h half (W_hh columns, kc 12..23) — skipped when h == 0
    if (!hz) {
#pragma unroll
        for (int kc = 0; kc < 12; ++kc) {
            bf16x8 a0 = av0 ? *(const bf16x8*)(hr0 + kc * 32) : zf;
            bf16x8 a1 = (do2 && av1) ? *(const bf16x8*)(hr1 + kc * 32) : zf;
            const size_t kb = (size_t)(12 + kc) * 512;
#pragma unroll
            for (int j = 0; j < 2; ++j) {
                const bf16x8 bR = *(const bf16x8*)(Wl + oR[j] + kb);
                const bf16x8 bZ = *(const bf16x8*)(Wl + oZ[j] + kb);
                const bf16x8 bN = *(const bf16x8*)(Wl + oN[j] + kb);
                ar[j][0]  = MFMA(a0, bR, ar[j][0]);
                az[j][0]  = MFMA(a0, bZ, az[j][0]);
                an2[j][0] = MFMA(a0, bN, an2[j][0]);
                if (do2) {
                    ar[j][1]  = MFMA(a1, bR, ar[j][1]);
                    az[j][1]  = MFMA(a1, bZ, az[j][1]);
                    an2[j][1] = MFMA(a1, bN, an2[j][1]);
                }
            }
        }
    }

    // epilogue: lane-local GRU update; at t==7 also node-mean + parent h0
#pragma unroll
    for (int j = 0; j < 2; ++j)
#pragma unroll
        for (int mt = 0; mt < 2; ++mt) {
            if (mt && !do2) break;
            float s4 = 0.0f;
#pragma unroll
            for (int r = 0; r < 4; ++r) {
                const int m = m0 + mt * 16 + quad * 4 + r;
                if (m < P) {
                    const size_t idx = (size_t)m * 384 + dj[j];
                    const float rv = sigmoid_(ar[j][mt][r] + br[j]);
                    const float zv = sigmoid_(az[j][mt][r] + bz[j]);
                    const float nv = tanh_(an1[j][mt][r] + bi[j]
                                           + rv * (an2[j][mt][r] + bh[j]));
                    const float hn = (1.0f - zv) * nv + zv * hp[j][mt][r];
                    s4 += hn;
                    if (!last) {
                        HT[(size_t)(t + 1) * N + idx] = hn;
                        HB[(size_t)(t + 1) * N + idx] = to_bf16(hn);
                    } else {
                        // node out = mean(h1..h8) = (h1..h6 + hp(=h7) + hn)/8
                        float xs = hn + hp[j][mt][r];
#pragma unroll
                        for (int s = 1; s <= 6; ++s) xs += HT[(size_t)s * N + idx];
                        const float xo = xs * 0.125f;
                        Xo[idx] = to_bf16(xo);
                        if (fout != nullptr && m == 0) fout[dj[j]] = xo;
                    }
                }
            }
            // parent h0 = mean of this node's 8 children h8 (quad pairs (0,1),(2,3))
            if (last && HTn != nullptr) {
                const float o = __shfl_xor(s4, 16, 64);
                if ((quad & 1) == 0) {
                    const int ti = (m0 >> 4) + mt;
                    const int pnode = 2 * ti + (quad >> 1);
                    if (pnode < Pn) {
                        const float h0 = (s4 + o) * 0.125f;
                        HTn[(size_t)pnode * 384 + dj[j]] = h0;
                        HBn[(size_t)pnode * 384 + dj[j]] = to_bf16(h0);
                    }
                }
            }
        }
}

extern "C" void kernel_launch(void* const* d_in, const int* in_sizes, int n_in,
                              void* d_out, int out_size, void* d_ws, size_t ws_size,
                              hipStream_t stream) {
    const int*   tok   = (const int*)d_in[0];
    const float* table = (const float*)d_in[1];
    const float* w_ih  = (const float*)d_in[2];
    const float* w_hh  = (const float*)d_in[3];
    const float* b_ih  = (const float*)d_in[4];
    const float* b_hh  = (const float*)d_in[5];
    float* out = (float*)d_out;

    char* ws = (char*)d_ws;
    size_t off = 0;
    auto alloc = [&](size_t bytes) -> void* {
        void* p = ws + off;
        off = (off + bytes + 255) & ~(size_t)255;
        return p;
    };
    ushort* wswz = (ushort*)alloc((size_t)1152 * 768 * 2);
    ushort* XA   = (ushort*)alloc((size_t)32768 * 384 * 2);

    struct Lvl { ushort *HB, *Xo; float *HT; int P; };
    auto mk = [&](int P) -> Lvl {
        Lvl l; l.P = P;
        size_t N = (size_t)P * 384;
        l.HT = (float*) alloc(8 * N * 4);
        l.HB = (ushort*)alloc(8 * N * 2);
        l.Xo = (ushort*)alloc(N * 2);
        return l;
    };
    Lvl L[5] = {mk(4096), mk(512), mk(64), mk(8), mk(1)};

    prep_w<<<(1152 * 96 + 255) / 256, 256, 0, stream>>>(w_ih, w_hh, wswz);
    embed_gather<<<(32768 * 48 + 255) / 256, 256, 0, stream>>>(tok, table, XA, 32768);

    for (int lv = 0; lv < 5; ++lv) {
        const ushort* Xc = (lv == 0) ? XA : L[lv - 1].Xo;
        int P = L[lv].P;
        int Pn = (lv < 4) ? L[lv + 1].P : 0;
        float*  HTn = (lv < 4) ? L[lv + 1].HT : nullptr;
        ushort* HBn = (lv < 4) ? L[lv + 1].HB : nullptr;
        int gx = (P + 127) / 128;
        gx = (gx + 7) & ~7;                 // pad for XCD colocation of ds-groups
        dim3 grid(gx, 12);
        for (int t = 0; t < 8; ++t) {
            int flags = ((lv == 0 && t == 0) ? 1 : 0) | (t == 7 ? 2 : 0);
            gru_step<<<grid, 256, 0, stream>>>(
                Xc, L[lv].HB, L[lv].HT, wswz, b_ih, b_hh, L[lv].Xo,
                (t == 7) ? HTn : nullptr, HBn, (lv == 4 && t == 7) ? out : nullptr,
                P, Pn, t, flags);
        }
    }
}

// Round 9
// 811.510 us; speedup vs baseline: 2.7387x; 1.1486x over previous
//
#include <hip/hip_runtime.h>
#include <hip/hip_bf16.h>
#include <stdint.h>

typedef float f32x4 __attribute__((ext_vector_type(4)));
typedef short bf16x8 __attribute__((ext_vector_type(8)));

__device__ __forceinline__ ushort to_bf16(float f) {
    union { float f; uint32_t u; } v; v.f = f;
    uint32_t u = v.u;
    return (ushort)((u + 0x7fffu + ((u >> 16) & 1u)) >> 16);   // RNE
}
__device__ __forceinline__ float sigmoid_(float x) { return 1.0f / (1.0f + __expf(-x)); }
__device__ __forceinline__ float tanh_(float x)    { return 1.0f - 2.0f / (__expf(2.0f * x) + 1.0f); }

// Swizzled concat weight W'[g][k] = (k<384 ? w_ih : w_hh), bf16; fragment layout:
// elem ((tile*24 + kc)*64 + quad*16 + (g&15))*8 + j  for k = kc*32 + quad*8 + j
__global__ void prep_w(const float* __restrict__ w_ih, const float* __restrict__ w_hh,
                       ushort* __restrict__ wswz) {
    int tid = blockIdx.x * blockDim.x + threadIdx.x;   // 1152 * 96
    if (tid >= 1152 * 96) return;
    int g  = tid / 96;
    int k  = (tid % 96) * 8;
    int kc = k >> 5;
    int q  = (k >> 3) & 3;
    int tile = g >> 4;
    int lane = q * 16 + (g & 15);
    ushort* dst = wswz + ((size_t)(tile * 24 + kc) * 64 + lane) * 8;
    const float* src = (k < 384) ? (w_ih + (size_t)g * 384 + k)
                                 : (w_hh + (size_t)g * 384 + (k - 384));
#pragma unroll
    for (int j = 0; j < 8; ++j) dst[j] = to_bf16(src[j]);
}

__global__ void embed_gather(const int* __restrict__ tok, const float* __restrict__ table,
                             ushort* __restrict__ xleaf, int n_leaves) {
    int tid = blockIdx.x * blockDim.x + threadIdx.x;   // n_leaves * 48
    if (tid >= n_leaves * 48) return;
    int leaf = tid / 48, i = tid % 48;
    const float* src = table + (size_t)tok[leaf] * 384 + i * 8;
    bf16x8 v;
#pragma unroll
    for (int j = 0; j < 8; ++j) v[j] = (short)to_bf16(src[j]);
    *(bf16x8*)(xleaf + (size_t)leaf * 384 + i * 8) = v;
}

#define MFMA(a, b, c) __builtin_amdgcn_mfma_f32_16x16x32_bf16((a), (b), (c), 0, 0, 0)

__device__ __forceinline__ bf16x8 cvt8(f32x4 a, f32x4 b) {
    bf16x8 o;
    o[0] = (short)to_bf16(a[0]); o[1] = (short)to_bf16(a[1]);
    o[2] = (short)to_bf16(a[2]); o[3] = (short)to_bf16(a[3]);
    o[4] = (short)to_bf16(b[0]); o[5] = (short)to_bf16(b[1]);
    o[6] = (short)to_bf16(b[2]); o[7] = (short)to_bf16(b[3]);
    return o;
}

// One GRU step, one launch (launch boundary = the barrier; in-kernel cross-block
// barriers fence-storm — measured r6/r7). No LDS. Block = 256 thr (4 waves);
// wave owns 32 rows (2 m-tiles); block owns 16 dims (ds = blockIdx.y in [0,24)),
// gate triple (r,z,n) -> GRU update lane-local.
// h state: f32 HT ONLY (8 slots; slot t = h entering step t). MFMA A-fragments
// for h are built on the fly (float4 x2 -> RNE bf16x8), identical numerics to a
// stored-bf16 mirror but HALF the h traffic -> per-XCD step working set
// (W 1.77 + x .39 + HT r .79 + HT w .79) = 3.74 MB < 4 MiB L2, so weights stay
// L2-resident across all 8 steps (r8's 44 MB/step FETCH was W thrash at 4.5 MB).
// Grid (gx, 24), gx % 8 == 0 (for P>=128) colocates a group's 24 ds-blocks on
// one XCD. flags: 1 = h_prev zero (leaf t0), 2 = last step.
__global__ __launch_bounds__(256, 4)
void gru_step(const ushort* __restrict__ Xc, float* __restrict__ HT,
              const ushort* __restrict__ W, const float* __restrict__ b_ih,
              const float* __restrict__ b_hh, ushort* __restrict__ Xo,
              float* __restrict__ HTn, float* __restrict__ fout,
              int P, int Pn, int t, int flags) {
    const int wave = threadIdx.x >> 6, lane = threadIdx.x & 63;
    const int quad = lane >> 4, col = lane & 15;
    const int m0 = (blockIdx.x * 4 + wave) * 32;
    if (m0 >= P) return;
    const int ds = blockIdx.y;
    const bool hz = (flags & 1) != 0, last = (flags & 2) != 0;
    const bool do2 = (m0 + 16) < P;                  // wave-uniform
    const int child = 7 - t;
    const size_t N = (size_t)P * 384;

    const float* HTp = HT + (size_t)t * N;
    float*       HTc = HT + (size_t)(t + 1) * N;

    const int par0 = m0 + col, par1 = m0 + 16 + col;
    const bool av0 = par0 < P, av1 = par1 < P;
    const ushort* xr0 = Xc + ((size_t)par0 * 8 + child) * 384 + quad * 8;
    const ushort* xr1 = Xc + ((size_t)par1 * 8 + child) * 384 + quad * 8;
    const float*  hr0 = HTp + (size_t)par0 * 384 + quad * 8;
    const float*  hr1 = HTp + (size_t)par1 * 384 + quad * 8;
    const ushort* Wl = W + (size_t)lane * 8;
    const size_t oR = (size_t)ds * 12288;
    const size_t oZ = (size_t)(24 + ds) * 12288;
    const size_t oN = (size_t)(48 + ds) * 12288;

    const int d = ds * 16 + col;
    const float br = b_ih[d] + b_hh[d];
    const float bz = b_ih[384 + d] + b_hh[384 + d];
    const float bi = b_ih[768 + d], bh = b_hh[768 + d];
    float hp[2][4];
#pragma unroll
    for (int mt = 0; mt < 2; ++mt)
#pragma unroll
        for (int r = 0; r < 4; ++r) {
            const int m = m0 + mt * 16 + quad * 4 + r;
            hp[mt][r] = (!hz && m < P) ? HTp[(size_t)m * 384 + d] : 0.0f;
        }

    const f32x4 z4 = (f32x4){0.f, 0.f, 0.f, 0.f};
    const bf16x8 zf = (bf16x8){0, 0, 0, 0, 0, 0, 0, 0};
    f32x4 ar0 = z4, az0 = z4, an10 = z4, an20 = z4;
    f32x4 ar1 = z4, az1 = z4, an11 = z4, an21 = z4;

    // x half (W_ih columns, kc 0..11), A = bf16 x
#pragma unroll
    for (int kc = 0; kc < 12; ++kc) {
        bf16x8 a0 = av0 ? *(const bf16x8*)(xr0 + kc * 32) : zf;
        bf16x8 a1 = (do2 && av1) ? *(const bf16x8*)(xr1 + kc * 32) : zf;
        const size_t kb = (size_t)kc * 512;
        const bf16x8 bR = *(const bf16x8*)(Wl + oR + kb);
        const bf16x8 bZ = *(const bf16x8*)(Wl + oZ + kb);
        const bf16x8 bN = *(const bf16x8*)(Wl + oN + kb);
        ar0  = MFMA(a0, bR, ar0);
        az0  = MFMA(a0, bZ, az0);
        an10 = MFMA(a0, bN, an10);
        if (do2) {
            ar1  = MFMA(a1, bR, ar1);
            az1  = MFMA(a1, bZ, az1);
            an11 = MFMA(a1, bN, an11);
        }
    }
    // h half (W_hh columns, kc 12..23), A = f32 h -> on-the-fly bf16 (RNE)
    if (!hz) {
#pragma unroll
        for (int kc = 0; kc < 12; ++kc) {
            bf16x8 a0 = zf, a1 = zf;
            if (av0) {
                const f32x4* s = (const f32x4*)(hr0 + kc * 32);
                a0 = cvt8(s[0], s[1]);
            }
            if (do2 && av1) {
                const f32x4* s = (const f32x4*)(hr1 + kc * 32);
                a1 = cvt8(s[0], s[1]);
            }
            const size_t kb = (size_t)(12 + kc) * 512;
            const bf16x8 bR = *(const bf16x8*)(Wl + oR + kb);
            const bf16x8 bZ = *(const bf16x8*)(Wl + oZ + kb);
            const bf16x8 bN = *(const bf16x8*)(Wl + oN + kb);
            ar0  = MFMA(a0, bR, ar0);
            az0  = MFMA(a0, bZ, az0);
            an20 = MFMA(a0, bN, an20);
            if (do2) {
                ar1  = MFMA(a1, bR, ar1);
                az1  = MFMA(a1, bZ, az1);
                an21 = MFMA(a1, bN, an21);
            }
        }
    }

    // epilogue: lane-local GRU update; at t==7 node-mean + parent h0
#pragma unroll
    for (int mt = 0; mt < 2; ++mt) {
        if (mt && !do2) break;
        const f32x4 ar  = mt ? ar1  : ar0;
        const f32x4 az  = mt ? az1  : az0;
        const f32x4 an1 = mt ? an11 : an10;
        const f32x4 an2 = mt ? an21 : an20;
        float s4 = 0.0f;
#pragma unroll
        for (int r = 0; r < 4; ++r) {
            const int m = m0 + mt * 16 + quad * 4 + r;
            if (m < P) {
                const size_t idx = (size_t)m * 384 + d;
                const float rv = sigmoid_(ar[r] + br);
                const float zv = sigmoid_(az[r] + bz);
                const float nv = tanh_(an1[r] + bi + rv * (an2[r] + bh));
                const float hn = (1.0f - zv) * nv + zv * hp[mt][r];
                s4 += hn;
                if (!last) {
                    HTc[idx] = hn;
                } else {
                    // node out = mean(h1..h8) = (slots 1..6 + hp(=h7) + hn)/8
                    float xs = hn + hp[mt][r];
#pragma unroll
                    for (int s = 1; s <= 6; ++s) xs += HT[(size_t)s * N + idx];
                    const float xo = xs * 0.125f;
                    Xo[idx] = to_bf16(xo);
                    if (fout != nullptr && m == 0) fout[d] = xo;
                }
            }
        }
        // parent h0 = mean of this node's 8 children h8 (quad pairs (0,1),(2,3))
        if (last && HTn != nullptr) {
            const float o = __shfl_xor(s4, 16, 64);
            if ((quad & 1) == 0) {
                const int ti = (m0 >> 4) + mt;
                const int pnode = 2 * ti + (quad >> 1);
                if (pnode < Pn)
                    HTn[(size_t)pnode * 384 + d] = (s4 + o) * 0.125f;
            }
        }
    }
}

extern "C" void kernel_launch(void* const* d_in, const int* in_sizes, int n_in,
                              void* d_out, int out_size, void* d_ws, size_t ws_size,
                              hipStream_t stream) {
    const int*   tok   = (const int*)d_in[0];
    const float* table = (const float*)d_in[1];
    const float* w_ih  = (const float*)d_in[2];
    const float* w_hh  = (const float*)d_in[3];
    const float* b_ih  = (const float*)d_in[4];
    const float* b_hh  = (const float*)d_in[5];
    float* out = (float*)d_out;

    char* ws = (char*)d_ws;
    size_t off = 0;
    auto alloc = [&](size_t bytes) -> void* {
        void* p = ws + off;
        off = (off + bytes + 255) & ~(size_t)255;
        return p;
    };
    ushort* wswz = (ushort*)alloc((size_t)1152 * 768 * 2);
    ushort* XA   = (ushort*)alloc((size_t)32768 * 384 * 2);

    struct Lvl { ushort* Xo; float* HT; int P; };
    auto mk = [&](int P) -> Lvl {
        Lvl l; l.P = P;
        size_t N = (size_t)P * 384;
        l.HT = (float*) alloc(8 * N * 4);   // f32 h slots 0..7
        l.Xo = (ushort*)alloc(N * 2);
        return l;
    };
    Lvl L[5] = {mk(4096), mk(512), mk(64), mk(8), mk(1)};

    prep_w<<<(1152 * 96 + 255) / 256, 256, 0, stream>>>(w_ih, w_hh, wswz);
    embed_gather<<<(32768 * 48 + 255) / 256, 256, 0, stream>>>(tok, table, XA, 32768);

    for (int lv = 0; lv < 5; ++lv) {
        const ushort* Xc = (lv == 0) ? XA : L[lv - 1].Xo;
        int P = L[lv].P;
        int Pn = (lv < 4) ? L[lv + 1].P : 0;
        float* HTn = (lv < 4) ? L[lv + 1].HT : nullptr;
        int gx = (P + 127) / 128;
        if (P >= 128) gx = (gx + 7) & ~7;   // XCD colocation of a group's ds-blocks
        dim3 grid(gx, 24);
        for (int t = 0; t < 8; ++t) {
            int flags = ((lv == 0 && t == 0) ? 1 : 0) | (t == 7 ? 2 : 0);
            gru_step<<<grid, 256, 0, stream>>>(
                Xc, L[lv].HT, wswz, b_ih, b_hh, L[lv].Xo,
                (t == 7) ? HTn : nullptr, (lv == 4 && t == 7) ? out : nullptr,
                P, Pn, t, flags);
        }
    }
}